// Round 1
// baseline (898.947 us; speedup 1.0000x reference)
//
#include <hip/hip_runtime.h>

#define NN 50000
#define NE 400000
// NODE_IN = HID = 16, EDGE_IN = 8

// ---------------------------------------------------------------------------
// Edge kernel: for each edge e
//   hid  = relu(edge_attr[e] @ w1 + b1)            [16]
//   W    = (hid @ w2 + b2).reshape(16,16)          (i,o)
//   msg  = x[src[e]] @ W                           [16]
//   atomicAdd into agg[dst[e]]; optionally count edges per dst.
// Shapes identical for both layers (in=16, out=16, edge_in=8).
// ---------------------------------------------------------------------------
__global__ __launch_bounds__(256) void edge_kernel(
    const float* __restrict__ xin,   // [N,16]
    const float* __restrict__ ea,    // [E,8]
    const int*   __restrict__ eidx,  // [2,E] (int32)
    const float* __restrict__ w1,    // [8,16]
    const float* __restrict__ b1,    // [16]
    const float* __restrict__ w2,    // [16,256]
    const float* __restrict__ b2,    // [256]
    float* __restrict__ agg,         // [N,16] (pre-zeroed)
    float* __restrict__ cnt,         // [N]    (pre-zeroed)
    int do_cnt)
{
    int e = blockIdx.x * blockDim.x + threadIdx.x;
    if (e >= NE) return;

    int s = eidx[e];
    int d = eidx[NE + e];

    // edge attributes (8 floats, 32B aligned)
    const float4* eav = (const float4*)(ea + (size_t)e * 8);
    float4 a0 = eav[0], a1 = eav[1];
    float a[8] = {a0.x, a0.y, a0.z, a0.w, a1.x, a1.y, a1.z, a1.w};

    // hidden = relu(a @ w1 + b1)
    float hid[16];
#pragma unroll
    for (int j = 0; j < 16; ++j) hid[j] = b1[j];
#pragma unroll
    for (int c = 0; c < 8; ++c) {
#pragma unroll
        for (int j = 0; j < 16; ++j) hid[j] += a[c] * w1[c * 16 + j];
    }
#pragma unroll
    for (int j = 0; j < 16; ++j) hid[j] = fmaxf(hid[j], 0.0f);

    // gather source features (64B, aligned)
    float xs[16];
    {
        const float4* xv = (const float4*)(xin + (size_t)s * 16);
        float4 v0 = xv[0], v1 = xv[1], v2 = xv[2], v3 = xv[3];
        xs[0]=v0.x; xs[1]=v0.y; xs[2]=v0.z; xs[3]=v0.w;
        xs[4]=v1.x; xs[5]=v1.y; xs[6]=v1.z; xs[7]=v1.w;
        xs[8]=v2.x; xs[9]=v2.y; xs[10]=v2.z; xs[11]=v2.w;
        xs[12]=v3.x; xs[13]=v3.y; xs[14]=v3.z; xs[15]=v3.w;
    }

    // msg[o] = sum_i xs[i]*b2[i*16+o] + sum_k sum_i hid[k]*xs[i]*w2[k*256+i*16+o]
    float msg[16];
#pragma unroll
    for (int o = 0; o < 16; ++o) msg[o] = 0.0f;
#pragma unroll
    for (int i = 0; i < 16; ++i) {
#pragma unroll
        for (int o = 0; o < 16; ++o) msg[o] += xs[i] * b2[i * 16 + o];
    }
#pragma unroll
    for (int k = 0; k < 16; ++k) {
#pragma unroll
        for (int i = 0; i < 16; ++i) {
            float p = hid[k] * xs[i];
#pragma unroll
            for (int o = 0; o < 16; ++o) msg[o] += p * w2[k * 256 + i * 16 + o];
        }
    }

    float* dstp = agg + (size_t)d * 16;
#pragma unroll
    for (int o = 0; o < 16; ++o) atomicAdd(dstp + o, msg[o]);
    if (do_cnt) atomicAdd(cnt + d, 1.0f);
}

// ---------------------------------------------------------------------------
// Node update layer 1: h1 = relu(agg / max(cnt,1) + x @ root + bias)
// ---------------------------------------------------------------------------
__global__ __launch_bounds__(256) void node1_kernel(
    const float* __restrict__ xin,   // [N,16]
    const float* __restrict__ agg,   // [N,16]
    const float* __restrict__ cnt,   // [N]
    const float* __restrict__ root,  // [16,16]
    const float* __restrict__ bias,  // [16]
    float* __restrict__ out)         // [N,16]
{
    int n = blockIdx.x * blockDim.x + threadIdx.x;
    if (n >= NN) return;
    float inv = 1.0f / fmaxf(cnt[n], 1.0f);

    float xs[16], acc[16];
    const float4* xv = (const float4*)(xin + (size_t)n * 16);
    const float4* av = (const float4*)(agg + (size_t)n * 16);
#pragma unroll
    for (int q = 0; q < 4; ++q) {
        float4 v = xv[q];
        xs[q*4+0]=v.x; xs[q*4+1]=v.y; xs[q*4+2]=v.z; xs[q*4+3]=v.w;
        float4 g = av[q];
        acc[q*4+0]=g.x*inv; acc[q*4+1]=g.y*inv; acc[q*4+2]=g.z*inv; acc[q*4+3]=g.w*inv;
    }
#pragma unroll
    for (int o = 0; o < 16; ++o) acc[o] += bias[o];
#pragma unroll
    for (int i = 0; i < 16; ++i) {
#pragma unroll
        for (int o = 0; o < 16; ++o) acc[o] += xs[i] * root[i * 16 + o];
    }
    float* op = out + (size_t)n * 16;
#pragma unroll
    for (int o = 0; o < 16; ++o) op[o] = fmaxf(acc[o], 0.0f);
}

// ---------------------------------------------------------------------------
// Node update layer 2 fused with q-head:
//   h2 = relu(agg / max(cnt,1) + h1 @ root2 + bias2)
//   out[n] = h2 @ q_w + q_b
// ---------------------------------------------------------------------------
__global__ __launch_bounds__(256) void node2q_kernel(
    const float* __restrict__ xin,   // h1 [N,16]
    const float* __restrict__ agg,   // [N,16]
    const float* __restrict__ cnt,   // [N]
    const float* __restrict__ root,  // [16,16]
    const float* __restrict__ bias,  // [16]
    const float* __restrict__ qw,    // [16]
    const float* __restrict__ qb,    // [1]
    float* __restrict__ out)         // [N]
{
    int n = blockIdx.x * blockDim.x + threadIdx.x;
    if (n >= NN) return;
    float inv = 1.0f / fmaxf(cnt[n], 1.0f);

    float xs[16], acc[16];
    const float4* xv = (const float4*)(xin + (size_t)n * 16);
    const float4* av = (const float4*)(agg + (size_t)n * 16);
#pragma unroll
    for (int q = 0; q < 4; ++q) {
        float4 v = xv[q];
        xs[q*4+0]=v.x; xs[q*4+1]=v.y; xs[q*4+2]=v.z; xs[q*4+3]=v.w;
        float4 g = av[q];
        acc[q*4+0]=g.x*inv; acc[q*4+1]=g.y*inv; acc[q*4+2]=g.z*inv; acc[q*4+3]=g.w*inv;
    }
#pragma unroll
    for (int o = 0; o < 16; ++o) acc[o] += bias[o];
#pragma unroll
    for (int i = 0; i < 16; ++i) {
#pragma unroll
        for (int o = 0; o < 16; ++o) acc[o] += xs[i] * root[i * 16 + o];
    }
    float q = qb[0];
#pragma unroll
    for (int o = 0; o < 16; ++o) q += fmaxf(acc[o], 0.0f) * qw[o];
    out[n] = q;
}

extern "C" void kernel_launch(void* const* d_in, const int* in_sizes, int n_in,
                              void* d_out, int out_size, void* d_ws, size_t ws_size,
                              hipStream_t stream) {
    const float* x     = (const float*)d_in[0];
    const float* ea    = (const float*)d_in[1];
    const float* e1w1  = (const float*)d_in[2];
    const float* e1b1  = (const float*)d_in[3];
    const float* e1w2  = (const float*)d_in[4];
    const float* e1b2  = (const float*)d_in[5];
    const float* root1 = (const float*)d_in[6];
    const float* bias1 = (const float*)d_in[7];
    const float* e2w1  = (const float*)d_in[8];
    const float* e2b1  = (const float*)d_in[9];
    const float* e2w2  = (const float*)d_in[10];
    const float* e2b2  = (const float*)d_in[11];
    const float* root2 = (const float*)d_in[12];
    const float* bias2 = (const float*)d_in[13];
    const float* qw    = (const float*)d_in[14];
    const float* qb    = (const float*)d_in[15];
    const int*   eidx  = (const int*)d_in[16];

    float* ws  = (float*)d_ws;
    float* cnt = ws;                      // N
    float* agg = ws + NN;                 // 16N
    float* h1  = ws + (size_t)17 * NN;    // 16N

    // zero cnt + agg
    hipMemsetAsync(d_ws, 0, (size_t)17 * NN * sizeof(float), stream);

    int eblocks = (NE + 255) / 256;
    int nblocks = (NN + 255) / 256;

    // layer 1
    edge_kernel<<<eblocks, 256, 0, stream>>>(x, ea, eidx, e1w1, e1b1, e1w2, e1b2,
                                             agg, cnt, 1);
    node1_kernel<<<nblocks, 256, 0, stream>>>(x, agg, cnt, root1, bias1, h1);

    // re-zero agg for layer 2
    hipMemsetAsync(agg, 0, (size_t)16 * NN * sizeof(float), stream);

    // layer 2 (+ fused q head)
    edge_kernel<<<eblocks, 256, 0, stream>>>(h1, ea, eidx, e2w1, e2b1, e2w2, e2b2,
                                             agg, cnt, 0);
    node2q_kernel<<<nblocks, 256, 0, stream>>>(h1, agg, cnt, root2, bias2, qw, qb,
                                               (float*)d_out);
}

// Round 2
// 318.895 us; speedup vs baseline: 2.8189x; 2.8189x over previous
//
#include <hip/hip_runtime.h>

#define NN 50000
#define NE 400000

// ws layout (4B elements):
//   msg    float [0, 16*NE)
//   h1     float [16*NE, 16*NE + 16*NN)
//   offs   int   [A, A+NN+1)         A = 16*NE + 16*NN
//   cursor int   [A+NN+1, A+2*NN+1)
//   order  int   [A+2*NN+1, A+2*NN+1+NE)

// ---------------------------------------------------------------------------
// CSR build
// ---------------------------------------------------------------------------
__global__ __launch_bounds__(256) void hist_kernel(
    const int* __restrict__ edst, int* __restrict__ cnt)
{
    int e = blockIdx.x * 256 + threadIdx.x;
    if (e < NE) atomicAdd(&cnt[edst[e]], 1);
}

#define SCAN_T 1024
__global__ __launch_bounds__(SCAN_T) void scan_kernel(
    int* __restrict__ cnt /* in: counts, out: exclusive prefix (cursor) */,
    int* __restrict__ offs /* [NN+1] */)
{
    __shared__ int wsum[SCAN_T / 64];
    __shared__ int carry_s;
    int tid = threadIdx.x;
    if (tid == 0) carry_s = 0;
    __syncthreads();
    for (int base = 0; base < NN; base += SCAN_T) {
        int i = base + tid;
        int v = (i < NN) ? cnt[i] : 0;
        // wave-inclusive scan
        int incl = v;
#pragma unroll
        for (int d = 1; d < 64; d <<= 1) {
            int t = __shfl_up(incl, d, 64);
            if ((tid & 63) >= d) incl += t;
        }
        if ((tid & 63) == 63) wsum[tid >> 6] = incl;
        __syncthreads();
        if (tid < SCAN_T / 64) {
            int w = wsum[tid];
            int wincl = w;
#pragma unroll
            for (int d = 1; d < SCAN_T / 64; d <<= 1) {
                int t = __shfl_up(wincl, d, SCAN_T / 64);
                if (tid >= d) wincl += t;
            }
            wsum[tid] = wincl - w;  // exclusive offset of this wave
        }
        __syncthreads();
        int excl = incl - v + wsum[tid >> 6] + carry_s;
        if (i < NN) { offs[i] = excl; cnt[i] = excl; }
        __syncthreads();
        if (tid == SCAN_T - 1) carry_s = excl + v;
        __syncthreads();
    }
    if (tid == 0) offs[NN] = carry_s;
}

__global__ __launch_bounds__(256) void fill_kernel(
    const int* __restrict__ edst, int* __restrict__ cursor,
    int* __restrict__ order)
{
    int e = blockIdx.x * 256 + threadIdx.x;
    if (e < NE) {
        int p = atomicAdd(&cursor[edst[e]], 1);
        order[p] = e;
    }
}

// ---------------------------------------------------------------------------
// Edge message kernel: msg[e] = x[src[e]] @ W_e,
//   W_e = (relu(ea[e]@w1+b1) @ w2 + b2).reshape(16,16)
// Weights indexed with compile-time-uniform offsets -> scalar loads, so the
// inner 4096 MACs are v_fma with an SGPR operand.
// __launch_bounds__(256,2): allow up to 256 VGPRs so hid/xs/msg stay in regs.
// ---------------------------------------------------------------------------
__global__ __launch_bounds__(256, 2) void edge_msg_kernel(
    const float* __restrict__ xin,   // [N,16]
    const float* __restrict__ ea,    // [E,8]
    const int*   __restrict__ esrc,  // [E]
    const float* __restrict__ w1,    // [8,16]
    const float* __restrict__ b1,    // [16]
    const float* __restrict__ w2,    // [16,256]
    const float* __restrict__ b2,    // [256]
    float* __restrict__ msg)         // [E,16]
{
    int e = blockIdx.x * 256 + threadIdx.x;
    if (e >= NE) return;

    int s = esrc[e];

    const float4* eav = (const float4*)(ea + (size_t)e * 8);
    float4 a0 = eav[0], a1 = eav[1];
    float a[8] = {a0.x, a0.y, a0.z, a0.w, a1.x, a1.y, a1.z, a1.w};

    float hid[16];
#pragma unroll
    for (int j = 0; j < 16; ++j) hid[j] = b1[j];
#pragma unroll
    for (int c = 0; c < 8; ++c)
#pragma unroll
        for (int j = 0; j < 16; ++j) hid[j] += a[c] * w1[c * 16 + j];
#pragma unroll
    for (int j = 0; j < 16; ++j) hid[j] = fmaxf(hid[j], 0.0f);

    float xs[16];
    {
        const float4* xv = (const float4*)(xin + (size_t)s * 16);
        float4 v0 = xv[0], v1 = xv[1], v2 = xv[2], v3 = xv[3];
        xs[0]=v0.x; xs[1]=v0.y; xs[2]=v0.z; xs[3]=v0.w;
        xs[4]=v1.x; xs[5]=v1.y; xs[6]=v1.z; xs[7]=v1.w;
        xs[8]=v2.x; xs[9]=v2.y; xs[10]=v2.z; xs[11]=v2.w;
        xs[12]=v3.x; xs[13]=v3.y; xs[14]=v3.z; xs[15]=v3.w;
    }

    float msgv[16];
#pragma unroll
    for (int o = 0; o < 16; ++o) msgv[o] = 0.0f;
#pragma unroll
    for (int i = 0; i < 16; ++i)
#pragma unroll
        for (int o = 0; o < 16; ++o) msgv[o] += xs[i] * b2[i * 16 + o];
#pragma unroll
    for (int k = 0; k < 16; ++k)
#pragma unroll
        for (int i = 0; i < 16; ++i) {
            float p = hid[k] * xs[i];
#pragma unroll
            for (int o = 0; o < 16; ++o) msgv[o] += p * w2[k * 256 + i * 16 + o];
        }

    float4* mp = (float4*)(msg + (size_t)e * 16);
    mp[0] = make_float4(msgv[0],  msgv[1],  msgv[2],  msgv[3]);
    mp[1] = make_float4(msgv[4],  msgv[5],  msgv[6],  msgv[7]);
    mp[2] = make_float4(msgv[8],  msgv[9],  msgv[10], msgv[11]);
    mp[3] = make_float4(msgv[12], msgv[13], msgv[14], msgv[15]);
}

// ---------------------------------------------------------------------------
// Node kernels: 16 lanes per node; lane o handles channel o.
// Gather-mean over the node's CSR edge list (coalesced 64B reads/edge),
// then root transform via intra-group shuffles.
// ---------------------------------------------------------------------------
__global__ __launch_bounds__(256, 2) void node1_gather(
    const float* __restrict__ x,     // [N,16]
    const float* __restrict__ msg,   // [E,16]
    const int*   __restrict__ order, // [E]
    const int*   __restrict__ offs,  // [N+1]
    const float* __restrict__ root,  // [16,16]
    const float* __restrict__ bias,  // [16]
    float* __restrict__ out)         // [N,16]
{
    int t = blockIdx.x * 256 + threadIdx.x;
    int n = t >> 4;
    int o = t & 15;
    if (n >= NN) return;

    int j0 = offs[n], j1 = offs[n + 1];
    float sum = 0.0f;
    for (int j = j0; j < j1; ++j) {
        int e = order[j];
        sum += msg[(size_t)e * 16 + o];
    }
    float inv = 1.0f / (float)((j1 - j0) > 0 ? (j1 - j0) : 1);
    float acc = sum * inv + bias[o];

    float xo = x[(size_t)n * 16 + o];
#pragma unroll
    for (int i = 0; i < 16; ++i)
        acc += __shfl(xo, i, 16) * root[i * 16 + o];

    out[(size_t)n * 16 + o] = fmaxf(acc, 0.0f);
}

__global__ __launch_bounds__(256, 2) void node2q_gather(
    const float* __restrict__ h1,    // [N,16]
    const float* __restrict__ msg,   // [E,16]
    const int*   __restrict__ order, // [E]
    const int*   __restrict__ offs,  // [N+1]
    const float* __restrict__ root,  // [16,16]
    const float* __restrict__ bias,  // [16]
    const float* __restrict__ qw,    // [16]
    const float* __restrict__ qb,    // [1]
    float* __restrict__ out)         // [N]
{
    int t = blockIdx.x * 256 + threadIdx.x;
    int n = t >> 4;
    int o = t & 15;
    if (n >= NN) return;

    int j0 = offs[n], j1 = offs[n + 1];
    float sum = 0.0f;
    for (int j = j0; j < j1; ++j) {
        int e = order[j];
        sum += msg[(size_t)e * 16 + o];
    }
    float inv = 1.0f / (float)((j1 - j0) > 0 ? (j1 - j0) : 1);
    float acc = sum * inv + bias[o];

    float xo = h1[(size_t)n * 16 + o];
#pragma unroll
    for (int i = 0; i < 16; ++i)
        acc += __shfl(xo, i, 16) * root[i * 16 + o];

    float q = fmaxf(acc, 0.0f) * qw[o];
#pragma unroll
    for (int d = 8; d >= 1; d >>= 1) q += __shfl_down(q, d, 16);
    if (o == 0) out[n] = q + qb[0];
}

extern "C" void kernel_launch(void* const* d_in, const int* in_sizes, int n_in,
                              void* d_out, int out_size, void* d_ws, size_t ws_size,
                              hipStream_t stream) {
    const float* x     = (const float*)d_in[0];
    const float* ea    = (const float*)d_in[1];
    const float* e1w1  = (const float*)d_in[2];
    const float* e1b1  = (const float*)d_in[3];
    const float* e1w2  = (const float*)d_in[4];
    const float* e1b2  = (const float*)d_in[5];
    const float* root1 = (const float*)d_in[6];
    const float* bias1 = (const float*)d_in[7];
    const float* e2w1  = (const float*)d_in[8];
    const float* e2b1  = (const float*)d_in[9];
    const float* e2w2  = (const float*)d_in[10];
    const float* e2b2  = (const float*)d_in[11];
    const float* root2 = (const float*)d_in[12];
    const float* bias2 = (const float*)d_in[13];
    const float* qw    = (const float*)d_in[14];
    const float* qb    = (const float*)d_in[15];
    const int*   eidx  = (const int*)d_in[16];
    const int*   esrc  = eidx;
    const int*   edst  = eidx + NE;

    float* msg = (float*)d_ws;                       // 16*NE
    float* h1  = msg + (size_t)16 * NE;              // 16*NN
    int*   offs   = (int*)(h1 + (size_t)16 * NN);    // NN+1
    int*   cursor = offs + NN + 1;                   // NN
    int*   order  = cursor + NN;                     // NE

    int eblocks = (NE + 255) / 256;
    int nblocks = (NN * 16 + 255) / 256;  // 16 lanes per node

    // --- CSR build (edge_index identical for both layers) ---
    hipMemsetAsync(cursor, 0, (size_t)NN * sizeof(int), stream);
    hist_kernel<<<eblocks, 256, 0, stream>>>(edst, cursor);
    scan_kernel<<<1, SCAN_T, 0, stream>>>(cursor, offs);
    fill_kernel<<<eblocks, 256, 0, stream>>>(edst, cursor, order);

    // --- layer 1 ---
    edge_msg_kernel<<<eblocks, 256, 0, stream>>>(x, ea, esrc, e1w1, e1b1, e1w2,
                                                 e1b2, msg);
    node1_gather<<<nblocks, 256, 0, stream>>>(x, msg, order, offs, root1, bias1,
                                              h1);

    // --- layer 2 + q head ---
    edge_msg_kernel<<<eblocks, 256, 0, stream>>>(h1, ea, esrc, e2w1, e2b1, e2w2,
                                                 e2b2, msg);
    node2q_gather<<<nblocks, 256, 0, stream>>>(h1, msg, order, offs, root2,
                                               bias2, qw, qb, (float*)d_out);
}

// Round 3
// 277.481 us; speedup vs baseline: 3.2397x; 1.1493x over previous
//
#include <hip/hip_runtime.h>

#define NN 50000
#define NE 400000
#define HALF (NE / 2)

// ws layout (4B elements):
//   msg    float [0, 16*NE)                        (CSR-slot order)
//   h1     float [16*NE, 16*NE+16*NN)
//   offs   int   [A, A+NN+1)      A = 16*NE+16*NN
//   cursor int   [A+NN+1, A+2*NN+1)
//   pos    int   [A+2*NN+1, ... +NE)
//   bsum   int   [.. +256)

// ---------------------------------------------------------------------------
// CSR build: hist -> 3-phase scan -> fill (records slot per edge)
// ---------------------------------------------------------------------------
__global__ __launch_bounds__(256) void hist_kernel(
    const int* __restrict__ edst, int* __restrict__ cnt)
{
    int e = blockIdx.x * 256 + threadIdx.x;
    if (e < NE) atomicAdd(&cnt[edst[e]], 1);
}

__device__ __forceinline__ int block_excl_scan_256(int v, int tid)
{
    __shared__ int wsum[4];
    int lane = tid & 63, w = tid >> 6;
    int incl = v;
#pragma unroll
    for (int d = 1; d < 64; d <<= 1) {
        int t = __shfl_up(incl, d, 64);
        if (lane >= d) incl += t;
    }
    if (lane == 63) wsum[w] = incl;
    __syncthreads();
    if (tid == 0) {
        int s = 0;
#pragma unroll
        for (int k = 0; k < 4; ++k) { int t = wsum[k]; wsum[k] = s; s += t; }
    }
    __syncthreads();
    return incl - v + wsum[w];
}

// Phase A: per-block (256-wide) sums of cnt
__global__ __launch_bounds__(256) void scan_a_kernel(
    const int* __restrict__ cnt, int* __restrict__ bsum)
{
    __shared__ int wsum[4];
    int tid = threadIdx.x;
    int i = blockIdx.x * 256 + tid;
    int v = (i < NN) ? cnt[i] : 0;
#pragma unroll
    for (int d = 32; d >= 1; d >>= 1) v += __shfl_down(v, d, 64);
    if ((tid & 63) == 0) wsum[tid >> 6] = v;
    __syncthreads();
    if (tid == 0) bsum[blockIdx.x] = wsum[0] + wsum[1] + wsum[2] + wsum[3];
}

// Phase B: exclusive scan of block sums (nb <= 256), one block
__global__ __launch_bounds__(256) void scan_b_kernel(
    int* __restrict__ bsum, int nb, int* __restrict__ offs)
{
    int tid = threadIdx.x;
    int v = (tid < nb) ? bsum[tid] : 0;
    int excl = block_excl_scan_256(v, tid);
    if (tid < nb) bsum[tid] = excl;
    if (tid == nb - 1) offs[NN] = excl + v;
}

// Phase C: per-block exclusive scan + block offset -> offs & cursor
__global__ __launch_bounds__(256) void scan_c_kernel(
    const int* __restrict__ cnt, const int* __restrict__ bsum,
    int* __restrict__ offs, int* __restrict__ cursor)
{
    int tid = threadIdx.x;
    int i = blockIdx.x * 256 + tid;
    int v = (i < NN) ? cnt[i] : 0;
    int excl = block_excl_scan_256(v, tid) + bsum[blockIdx.x];
    if (i < NN) { offs[i] = excl; cursor[i] = excl; }
}

__global__ __launch_bounds__(256) void fill_kernel(
    const int* __restrict__ edst, int* __restrict__ cursor,
    int* __restrict__ pos)
{
    int e = blockIdx.x * 256 + threadIdx.x;
    if (e < NE) pos[e] = atomicAdd(&cursor[edst[e]], 1);
}

// ---------------------------------------------------------------------------
// Edge message kernel, 2 edges/thread: every scalar weight load feeds 2 FMAs.
// Writes msg directly into CSR slot pos[e] (scattered 64B stores) so the
// node gather is a pure streaming read.
// ---------------------------------------------------------------------------
__global__ __launch_bounds__(256, 2) void edge_msg2_kernel(
    const float* __restrict__ xin,   // [N,16]
    const float* __restrict__ ea,    // [E,8]
    const int*   __restrict__ esrc,  // [E]
    const int*   __restrict__ pos,   // [E]
    const float* __restrict__ w1,    // [8,16]
    const float* __restrict__ b1,    // [16]
    const float* __restrict__ w2,    // [16,256]
    const float* __restrict__ b2,    // [256]
    float* __restrict__ msg)         // [E,16] in slot order
{
    int t = blockIdx.x * 256 + threadIdx.x;
    if (t >= HALF) return;
    int e0 = t, e1 = t + HALF;

    int s0 = esrc[e0], s1 = esrc[e1];
    int p0 = pos[e0],  p1 = pos[e1];

    float a0[8], a1[8];
    {
        const float4* v = (const float4*)(ea + (size_t)e0 * 8);
        float4 u0 = v[0], u1 = v[1];
        a0[0]=u0.x; a0[1]=u0.y; a0[2]=u0.z; a0[3]=u0.w;
        a0[4]=u1.x; a0[5]=u1.y; a0[6]=u1.z; a0[7]=u1.w;
        v = (const float4*)(ea + (size_t)e1 * 8);
        u0 = v[0]; u1 = v[1];
        a1[0]=u0.x; a1[1]=u0.y; a1[2]=u0.z; a1[3]=u0.w;
        a1[4]=u1.x; a1[5]=u1.y; a1[6]=u1.z; a1[7]=u1.w;
    }

    float h0[16], h1v[16];
#pragma unroll
    for (int j = 0; j < 16; ++j) { float b = b1[j]; h0[j] = b; h1v[j] = b; }
#pragma unroll
    for (int c = 0; c < 8; ++c)
#pragma unroll
        for (int j = 0; j < 16; ++j) {
            float w = w1[c * 16 + j];
            h0[j]  += a0[c] * w;
            h1v[j] += a1[c] * w;
        }
#pragma unroll
    for (int j = 0; j < 16; ++j) {
        h0[j]  = fmaxf(h0[j], 0.0f);
        h1v[j] = fmaxf(h1v[j], 0.0f);
    }

    float xs0[16], xs1[16];
    {
        const float4* xv = (const float4*)(xin + (size_t)s0 * 16);
#pragma unroll
        for (int q = 0; q < 4; ++q) {
            float4 v = xv[q];
            xs0[q*4+0]=v.x; xs0[q*4+1]=v.y; xs0[q*4+2]=v.z; xs0[q*4+3]=v.w;
        }
        xv = (const float4*)(xin + (size_t)s1 * 16);
#pragma unroll
        for (int q = 0; q < 4; ++q) {
            float4 v = xv[q];
            xs1[q*4+0]=v.x; xs1[q*4+1]=v.y; xs1[q*4+2]=v.z; xs1[q*4+3]=v.w;
        }
    }

    float m0[16], m1[16];
#pragma unroll
    for (int o = 0; o < 16; ++o) { m0[o] = 0.0f; m1[o] = 0.0f; }
#pragma unroll
    for (int i = 0; i < 16; ++i)
#pragma unroll
        for (int o = 0; o < 16; ++o) {
            float w = b2[i * 16 + o];
            m0[o] += xs0[i] * w;
            m1[o] += xs1[i] * w;
        }
#pragma unroll
    for (int k = 0; k < 16; ++k)
#pragma unroll
        for (int i = 0; i < 16; ++i) {
            float q0 = h0[k]  * xs0[i];
            float q1 = h1v[k] * xs1[i];
#pragma unroll
            for (int o = 0; o < 16; ++o) {
                float w = w2[k * 256 + i * 16 + o];
                m0[o] += q0 * w;
                m1[o] += q1 * w;
            }
        }

    float4* mp = (float4*)(msg + (size_t)p0 * 16);
    mp[0] = make_float4(m0[0],  m0[1],  m0[2],  m0[3]);
    mp[1] = make_float4(m0[4],  m0[5],  m0[6],  m0[7]);
    mp[2] = make_float4(m0[8],  m0[9],  m0[10], m0[11]);
    mp[3] = make_float4(m0[12], m0[13], m0[14], m0[15]);
    mp = (float4*)(msg + (size_t)p1 * 16);
    mp[0] = make_float4(m1[0],  m1[1],  m1[2],  m1[3]);
    mp[1] = make_float4(m1[4],  m1[5],  m1[6],  m1[7]);
    mp[2] = make_float4(m1[8],  m1[9],  m1[10], m1[11]);
    mp[3] = make_float4(m1[12], m1[13], m1[14], m1[15]);
}

// ---------------------------------------------------------------------------
// Node kernels: 16 lanes per node, lane o = channel o. Messages are already
// in CSR order -> streaming read msg[j*16+o], no indirection.
// ---------------------------------------------------------------------------
__global__ __launch_bounds__(256, 2) void node1_gather(
    const float* __restrict__ x,     // [N,16]
    const float* __restrict__ msg,   // [E,16] slot order
    const int*   __restrict__ offs,  // [N+1]
    const float* __restrict__ root,  // [16,16]
    const float* __restrict__ bias,  // [16]
    float* __restrict__ out)         // [N,16]
{
    int t = blockIdx.x * 256 + threadIdx.x;
    int n = t >> 4;
    int o = t & 15;
    if (n >= NN) return;

    int j0 = offs[n], j1 = offs[n + 1];
    float sum = 0.0f;
    for (int j = j0; j < j1; ++j) sum += msg[(size_t)j * 16 + o];
    float inv = 1.0f / (float)((j1 - j0) > 0 ? (j1 - j0) : 1);
    float acc = sum * inv + bias[o];

    float xo = x[(size_t)n * 16 + o];
#pragma unroll
    for (int i = 0; i < 16; ++i)
        acc += __shfl(xo, i, 16) * root[i * 16 + o];

    out[(size_t)n * 16 + o] = fmaxf(acc, 0.0f);
}

__global__ __launch_bounds__(256, 2) void node2q_gather(
    const float* __restrict__ h1,    // [N,16]
    const float* __restrict__ msg,   // [E,16] slot order
    const int*   __restrict__ offs,  // [N+1]
    const float* __restrict__ root,  // [16,16]
    const float* __restrict__ bias,  // [16]
    const float* __restrict__ qw,    // [16]
    const float* __restrict__ qb,    // [1]
    float* __restrict__ out)         // [N]
{
    int t = blockIdx.x * 256 + threadIdx.x;
    int n = t >> 4;
    int o = t & 15;
    if (n >= NN) return;

    int j0 = offs[n], j1 = offs[n + 1];
    float sum = 0.0f;
    for (int j = j0; j < j1; ++j) sum += msg[(size_t)j * 16 + o];
    float inv = 1.0f / (float)((j1 - j0) > 0 ? (j1 - j0) : 1);
    float acc = sum * inv + bias[o];

    float xo = h1[(size_t)n * 16 + o];
#pragma unroll
    for (int i = 0; i < 16; ++i)
        acc += __shfl(xo, i, 16) * root[i * 16 + o];

    float q = fmaxf(acc, 0.0f) * qw[o];
#pragma unroll
    for (int d = 8; d >= 1; d >>= 1) q += __shfl_down(q, d, 16);
    if (o == 0) out[n] = q + qb[0];
}

extern "C" void kernel_launch(void* const* d_in, const int* in_sizes, int n_in,
                              void* d_out, int out_size, void* d_ws, size_t ws_size,
                              hipStream_t stream) {
    const float* x     = (const float*)d_in[0];
    const float* ea    = (const float*)d_in[1];
    const float* e1w1  = (const float*)d_in[2];
    const float* e1b1  = (const float*)d_in[3];
    const float* e1w2  = (const float*)d_in[4];
    const float* e1b2  = (const float*)d_in[5];
    const float* root1 = (const float*)d_in[6];
    const float* bias1 = (const float*)d_in[7];
    const float* e2w1  = (const float*)d_in[8];
    const float* e2b1  = (const float*)d_in[9];
    const float* e2w2  = (const float*)d_in[10];
    const float* e2b2  = (const float*)d_in[11];
    const float* root2 = (const float*)d_in[12];
    const float* bias2 = (const float*)d_in[13];
    const float* qw    = (const float*)d_in[14];
    const float* qb    = (const float*)d_in[15];
    const int*   eidx  = (const int*)d_in[16];
    const int*   esrc  = eidx;
    const int*   edst  = eidx + NE;

    float* msg = (float*)d_ws;                       // 16*NE
    float* h1  = msg + (size_t)16 * NE;              // 16*NN
    int*   offs   = (int*)(h1 + (size_t)16 * NN);    // NN+1
    int*   cursor = offs + NN + 1;                   // NN
    int*   pos    = cursor + NN;                     // NE
    int*   bsum   = pos + NE;                        // 256

    int eblocks  = (NE + 255) / 256;
    int e2blocks = (HALF + 255) / 256;
    int nblocks  = (NN * 16 + 255) / 256;
    int sblocks  = (NN + 255) / 256;   // 196

    // --- CSR build ---
    hipMemsetAsync(cursor, 0, (size_t)NN * sizeof(int), stream);
    hist_kernel<<<eblocks, 256, 0, stream>>>(edst, cursor);
    scan_a_kernel<<<sblocks, 256, 0, stream>>>(cursor, bsum);
    scan_b_kernel<<<1, 256, 0, stream>>>(bsum, sblocks, offs);
    scan_c_kernel<<<sblocks, 256, 0, stream>>>(cursor, bsum, offs, cursor);
    fill_kernel<<<eblocks, 256, 0, stream>>>(edst, cursor, pos);

    // --- layer 1 ---
    edge_msg2_kernel<<<e2blocks, 256, 0, stream>>>(x, ea, esrc, pos, e1w1, e1b1,
                                                   e1w2, e1b2, msg);
    node1_gather<<<nblocks, 256, 0, stream>>>(x, msg, offs, root1, bias1, h1);

    // --- layer 2 + q head ---
    edge_msg2_kernel<<<e2blocks, 256, 0, stream>>>(h1, ea, esrc, pos, e2w1, e2b1,
                                                   e2w2, e2b2, msg);
    node2q_gather<<<nblocks, 256, 0, stream>>>(h1, msg, offs, root2, bias2, qw,
                                               qb, (float*)d_out);
}

// Round 4
// 254.569 us; speedup vs baseline: 3.5312x; 1.0900x over previous
//
#include <hip/hip_runtime.h>

#define NN 50000
#define NE 400000
#define SCAN_N (2 * NN)
#define SA_BLOCKS ((SCAN_N + 255) / 256)   // 391
#define YSTRIDE 276                        // 272 + pad (keeps b128 align, spreads banks)

// ws layout (4B units):
//   msg      float [0, 16*NE)              25.6 MB   (dst-CSR slot order)
//   h1       float [16*NE, +16*NN)          3.2 MB
//   offs_all int   [A, A+2NN+1)             src offsets [0..NN], dst offsets at [NN..2NN]-NE
//   cursor   int   [.., +2NN)
//   ordsrc   int2  [.., +2*NE)              per src slot: {edge id, dst slot}
//   bsum     int   [.., +512)

// ---------------------------------------------------------------------------
// CSR build: combined src+dst histogram -> one 3-phase scan over 2N -> fill
// ---------------------------------------------------------------------------
__global__ __launch_bounds__(256) void hist2_kernel(
    const int* __restrict__ eidx, int* __restrict__ cnt)
{
    int e = blockIdx.x * 256 + threadIdx.x;
    if (e < NE) {
        atomicAdd(&cnt[eidx[e]], 1);            // src count
        atomicAdd(&cnt[NN + eidx[NE + e]], 1);  // dst count
    }
}

template <int NT>
__device__ __forceinline__ int block_excl_scan(int v, int tid)
{
    __shared__ int wsum[NT / 64];
    int lane = tid & 63, w = tid >> 6;
    int incl = v;
#pragma unroll
    for (int d = 1; d < 64; d <<= 1) {
        int t = __shfl_up(incl, d, 64);
        if (lane >= d) incl += t;
    }
    if (lane == 63) wsum[w] = incl;
    __syncthreads();
    if (tid == 0) {
        int s = 0;
#pragma unroll
        for (int k = 0; k < NT / 64; ++k) { int t = wsum[k]; wsum[k] = s; s += t; }
    }
    __syncthreads();
    return incl - v + wsum[w];
}

__global__ __launch_bounds__(256) void scan_a_kernel(
    const int* __restrict__ cnt, int* __restrict__ bsum)
{
    __shared__ int wsum[4];
    int tid = threadIdx.x;
    int i = blockIdx.x * 256 + tid;
    int v = (i < SCAN_N) ? cnt[i] : 0;
#pragma unroll
    for (int d = 32; d >= 1; d >>= 1) v += __shfl_down(v, d, 64);
    if ((tid & 63) == 0) wsum[tid >> 6] = v;
    __syncthreads();
    if (tid == 0) bsum[blockIdx.x] = wsum[0] + wsum[1] + wsum[2] + wsum[3];
}

__global__ __launch_bounds__(512) void scan_b_kernel(
    int* __restrict__ bsum, int* __restrict__ offs_all)
{
    int tid = threadIdx.x;
    int v = (tid < SA_BLOCKS) ? bsum[tid] : 0;
    int excl = block_excl_scan<512>(v, tid);
    if (tid < SA_BLOCKS) bsum[tid] = excl;
    if (tid == SA_BLOCKS - 1) offs_all[SCAN_N] = excl + v;  // = 2*NE
}

__global__ __launch_bounds__(256) void scan_c_kernel(
    int* __restrict__ cnt /* in: counts, out: cursor */,
    const int* __restrict__ bsum, int* __restrict__ offs_all)
{
    int tid = threadIdx.x;
    int i = blockIdx.x * 256 + tid;
    int v = (i < SCAN_N) ? cnt[i] : 0;
    int excl = block_excl_scan<256>(v, tid) + bsum[blockIdx.x];
    if (i < SCAN_N) { offs_all[i] = excl; cnt[i] = excl; }
}

__global__ __launch_bounds__(256) void fill2_kernel(
    const int* __restrict__ eidx, int* __restrict__ cursor,
    int2* __restrict__ ordsrc)
{
    int e = blockIdx.x * 256 + threadIdx.x;
    if (e < NE) {
        int s = eidx[e], d = eidx[NE + e];
        int ps = atomicAdd(&cursor[s], 1);
        int pd = atomicAdd(&cursor[NN + d], 1) - NE;
        ordsrc[ps] = make_int2(e, pd);
    }
}

// ---------------------------------------------------------------------------
// Fused edge kernel. Block = 16 src nodes.
// Phase 1: Y[node][k][o] = sum_i x[node,i]*w2[k,i,o]  (k<16), Y0 at slice 16
//          (b2). Stored in LDS, node stride YSTRIDE words.
// Phase 2: thread per out-edge slot j (src-CSR):
//          hid = relu(ea[e]@w1+b1); msg = Y0 + sum_k hid[k]*Y[k]
//          written to dst-CSR slot pd (so node gather streams).
// ---------------------------------------------------------------------------
__global__ __launch_bounds__(256) void edge_fused_kernel(
    const float* __restrict__ xin,    // [N,16]
    const float* __restrict__ ea,     // [E,8]
    const int2*  __restrict__ ordsrc, // [E] {eid, dst slot}
    const int*   __restrict__ offs_src, // [N+1]
    const float* __restrict__ w1,     // [8,16]
    const float* __restrict__ b1,     // [16]
    const float* __restrict__ w2,     // [16,256]
    const float* __restrict__ b2,     // [256]
    float* __restrict__ msg)          // [E,16] dst-slot order
{
    __shared__ float xl[16 * 16];
    __shared__ float Yl[16 * YSTRIDE];
    __shared__ int so[17];

    int tid = threadIdx.x;
    int n0 = blockIdx.x * 16;

    // stage x rows (coalesced) + src offsets
    {
        int node = tid >> 4, i = tid & 15;
        xl[tid] = xin[(size_t)(n0 + node) * 16 + i];
    }
    if (tid < 17) so[tid] = offs_src[n0 + tid];
    __syncthreads();

    int o = tid & 15;
    // ---- phase 1a: Y slices k=0..15; thread (k,o) keeps its 16 weights in regs
    {
        int k = tid >> 4;
        float w[16];
#pragma unroll
        for (int i = 0; i < 16; ++i) w[i] = w2[k * 256 + i * 16 + o];
#pragma unroll 4
        for (int node = 0; node < 16; ++node) {
            const float4* xr = (const float4*)&xl[node * 16];
            float4 x0 = xr[0], x1 = xr[1], x2 = xr[2], x3 = xr[3];
            float acc = x0.x * w[0] + x0.y * w[1] + x0.z * w[2] + x0.w * w[3]
                      + x1.x * w[4] + x1.y * w[5] + x1.z * w[6] + x1.w * w[7]
                      + x2.x * w[8] + x2.y * w[9] + x2.z * w[10] + x2.w * w[11]
                      + x3.x * w[12] + x3.y * w[13] + x3.z * w[14] + x3.w * w[15];
            Yl[node * YSTRIDE + k * 16 + o] = acc;
        }
    }
    // ---- phase 1b: Y0 slice (b2); thread (node,o)
    {
        int node = tid >> 4;
        float w[16];
#pragma unroll
        for (int i = 0; i < 16; ++i) w[i] = b2[i * 16 + o];
        const float4* xr = (const float4*)&xl[node * 16];
        float4 x0 = xr[0], x1 = xr[1], x2 = xr[2], x3 = xr[3];
        float acc = x0.x * w[0] + x0.y * w[1] + x0.z * w[2] + x0.w * w[3]
                  + x1.x * w[4] + x1.y * w[5] + x1.z * w[6] + x1.w * w[7]
                  + x2.x * w[8] + x2.y * w[9] + x2.z * w[10] + x2.w * w[11]
                  + x3.x * w[12] + x3.y * w[13] + x3.z * w[14] + x3.w * w[15];
        Yl[node * YSTRIDE + 256 + o] = acc;
    }
    __syncthreads();

    // ---- phase 2: one thread per out-edge slot
    int j0 = so[0], j1 = so[16];
    for (int j = j0 + tid; j < j1; j += 256) {
        int node = 0;
#pragma unroll
        for (int t = 1; t < 16; ++t) node += (j >= so[t]) ? 1 : 0;

        int2 od = ordsrc[j];
        int e = od.x, pd = od.y;

        const float4* av = (const float4*)(ea + (size_t)e * 8);
        float4 a0 = av[0], a1 = av[1];
        float a[8] = {a0.x, a0.y, a0.z, a0.w, a1.x, a1.y, a1.z, a1.w};

        float hid[16];
#pragma unroll
        for (int jj = 0; jj < 16; ++jj) hid[jj] = b1[jj];
#pragma unroll
        for (int c = 0; c < 8; ++c)
#pragma unroll
            for (int jj = 0; jj < 16; ++jj) hid[jj] += a[c] * w1[c * 16 + jj];
#pragma unroll
        for (int jj = 0; jj < 16; ++jj) hid[jj] = fmaxf(hid[jj], 0.0f);

        const float4* Yr = (const float4*)&Yl[node * YSTRIDE];
        float4 m0 = Yr[64], m1 = Yr[65], m2 = Yr[66], m3 = Yr[67];  // Y0
#pragma unroll
        for (int k = 0; k < 16; ++k) {
            float hk = hid[k];
            float4 y0 = Yr[k * 4 + 0], y1 = Yr[k * 4 + 1];
            float4 y2 = Yr[k * 4 + 2], y3 = Yr[k * 4 + 3];
            m0.x = fmaf(hk, y0.x, m0.x); m0.y = fmaf(hk, y0.y, m0.y);
            m0.z = fmaf(hk, y0.z, m0.z); m0.w = fmaf(hk, y0.w, m0.w);
            m1.x = fmaf(hk, y1.x, m1.x); m1.y = fmaf(hk, y1.y, m1.y);
            m1.z = fmaf(hk, y1.z, m1.z); m1.w = fmaf(hk, y1.w, m1.w);
            m2.x = fmaf(hk, y2.x, m2.x); m2.y = fmaf(hk, y2.y, m2.y);
            m2.z = fmaf(hk, y2.z, m2.z); m2.w = fmaf(hk, y2.w, m2.w);
            m3.x = fmaf(hk, y3.x, m3.x); m3.y = fmaf(hk, y3.y, m3.y);
            m3.z = fmaf(hk, y3.z, m3.z); m3.w = fmaf(hk, y3.w, m3.w);
        }
        float4* mp = (float4*)(msg + (size_t)pd * 16);
        mp[0] = m0; mp[1] = m1; mp[2] = m2; mp[3] = m3;
    }
}

// ---------------------------------------------------------------------------
// Node kernels: 16 lanes/node, lane o = channel o; msg streams in dst order.
// ---------------------------------------------------------------------------
__global__ __launch_bounds__(256) void node1_gather(
    const float* __restrict__ x, const float* __restrict__ msg,
    const int* __restrict__ offs_dst, /* offs_all+NN, values offset by NE */
    const float* __restrict__ root, const float* __restrict__ bias,
    float* __restrict__ out)
{
    int t = blockIdx.x * 256 + threadIdx.x;
    int n = t >> 4, o = t & 15;
    if (n >= NN) return;

    int j0 = offs_dst[n] - NE, j1 = offs_dst[n + 1] - NE;
    float sum = 0.0f;
    for (int j = j0; j < j1; ++j) sum += msg[(size_t)j * 16 + o];
    float inv = 1.0f / (float)((j1 - j0) > 0 ? (j1 - j0) : 1);
    float acc = sum * inv + bias[o];

    float xo = x[(size_t)n * 16 + o];
#pragma unroll
    for (int i = 0; i < 16; ++i)
        acc += __shfl(xo, i, 16) * root[i * 16 + o];

    out[(size_t)n * 16 + o] = fmaxf(acc, 0.0f);
}

__global__ __launch_bounds__(256) void node2q_gather(
    const float* __restrict__ h1, const float* __restrict__ msg,
    const int* __restrict__ offs_dst,
    const float* __restrict__ root, const float* __restrict__ bias,
    const float* __restrict__ qw, const float* __restrict__ qb,
    float* __restrict__ out)
{
    int t = blockIdx.x * 256 + threadIdx.x;
    int n = t >> 4, o = t & 15;
    if (n >= NN) return;

    int j0 = offs_dst[n] - NE, j1 = offs_dst[n + 1] - NE;
    float sum = 0.0f;
    for (int j = j0; j < j1; ++j) sum += msg[(size_t)j * 16 + o];
    float inv = 1.0f / (float)((j1 - j0) > 0 ? (j1 - j0) : 1);
    float acc = sum * inv + bias[o];

    float xo = h1[(size_t)n * 16 + o];
#pragma unroll
    for (int i = 0; i < 16; ++i)
        acc += __shfl(xo, i, 16) * root[i * 16 + o];

    float q = fmaxf(acc, 0.0f) * qw[o];
#pragma unroll
    for (int d = 8; d >= 1; d >>= 1) q += __shfl_down(q, d, 16);
    if (o == 0) out[n] = q + qb[0];
}

extern "C" void kernel_launch(void* const* d_in, const int* in_sizes, int n_in,
                              void* d_out, int out_size, void* d_ws, size_t ws_size,
                              hipStream_t stream) {
    const float* x     = (const float*)d_in[0];
    const float* ea    = (const float*)d_in[1];
    const float* e1w1  = (const float*)d_in[2];
    const float* e1b1  = (const float*)d_in[3];
    const float* e1w2  = (const float*)d_in[4];
    const float* e1b2  = (const float*)d_in[5];
    const float* root1 = (const float*)d_in[6];
    const float* bias1 = (const float*)d_in[7];
    const float* e2w1  = (const float*)d_in[8];
    const float* e2b1  = (const float*)d_in[9];
    const float* e2w2  = (const float*)d_in[10];
    const float* e2b2  = (const float*)d_in[11];
    const float* root2 = (const float*)d_in[12];
    const float* bias2 = (const float*)d_in[13];
    const float* qw    = (const float*)d_in[14];
    const float* qb    = (const float*)d_in[15];
    const int*   eidx  = (const int*)d_in[16];

    float* msg      = (float*)d_ws;                    // 16*NE
    float* h1       = msg + (size_t)16 * NE;           // 16*NN
    int*   offs_all = (int*)(h1 + (size_t)16 * NN);    // 2*NN+1
    int*   cursor   = offs_all + SCAN_N + 1;           // 2*NN
    int2*  ordsrc   = (int2*)(cursor + SCAN_N);        // NE int2
    int*   bsum     = (int*)(ordsrc + NE);             // 512

    int eblocks = (NE + 255) / 256;
    int gblocks = NN / 16;                 // 3125 (NN divisible by 16)
    int nblocks = (NN * 16 + 255) / 256;

    // --- CSR build (src + dst in one pass) ---
    hipMemsetAsync(cursor, 0, (size_t)SCAN_N * sizeof(int), stream);
    hist2_kernel<<<eblocks, 256, 0, stream>>>(eidx, cursor);
    scan_a_kernel<<<SA_BLOCKS, 256, 0, stream>>>(cursor, bsum);
    scan_b_kernel<<<1, 512, 0, stream>>>(bsum, offs_all);
    scan_c_kernel<<<SA_BLOCKS, 256, 0, stream>>>(cursor, bsum, offs_all);
    fill2_kernel<<<eblocks, 256, 0, stream>>>(eidx, cursor, ordsrc);

    // --- layer 1 ---
    edge_fused_kernel<<<gblocks, 256, 0, stream>>>(x, ea, ordsrc, offs_all,
                                                   e1w1, e1b1, e1w2, e1b2, msg);
    node1_gather<<<nblocks, 256, 0, stream>>>(x, msg, offs_all + NN, root1,
                                              bias1, h1);

    // --- layer 2 + q head ---
    edge_fused_kernel<<<gblocks, 256, 0, stream>>>(h1, ea, ordsrc, offs_all,
                                                   e2w1, e2b1, e2w2, e2b2, msg);
    node2q_gather<<<nblocks, 256, 0, stream>>>(h1, msg, offs_all + NN, root2,
                                               bias2, qw, qb, (float*)d_out);
}